// Round 1
// baseline (2632.173 us; speedup 1.0000x reference)
//
#include <hip/hip_runtime.h>
#include <math.h>

#define HH 32
#define NODE_IN 64
#define EDGE_IN 16
#define EDGE_H 128
#define ET 64   // edges per block in edge kernel

// ---------------- lin0: out = relu(n_feat @ lin0_w^T + b), h0 = out ----------------
__global__ void k_lin0(const float* __restrict__ nf, const float* __restrict__ w,
                       const float* __restrict__ b, float* __restrict__ out,
                       float* __restrict__ h0, int n) {
    __shared__ float nf_s[8][NODE_IN];
    __shared__ float w_s[HH][NODE_IN + 1];
    int t = threadIdx.x;
    for (int i = t; i < HH * NODE_IN; i += 256) w_s[i / NODE_IN][i % NODE_IN] = w[i];
    int n0 = blockIdx.x * 8;
    for (int i = t; i < 8 * NODE_IN; i += 256) {
        int nl = i / NODE_IN, k = i % NODE_IN;
        int nn = n0 + nl;
        nf_s[nl][k] = (nn < n) ? nf[(size_t)nn * NODE_IN + k] : 0.f;
    }
    __syncthreads();
    int nl = t >> 5, h = t & 31;
    int nn = n0 + nl;
    if (nn < n) {
        float acc = b[h];
        #pragma unroll
        for (int k = 0; k < NODE_IN; ++k) acc += nf_s[nl][k] * w_s[h][k];
        acc = fmaxf(acc, 0.f);
        out[(size_t)nn * HH + h] = acc;
        h0[(size_t)nn * HH + h] = acc;
    }
}

// ---------------- fused edge message kernel (recomputes r and We-slices) ----------------
// msg[e,o] = sum_h x[e,h] * ( sum_j r[e,j]*en2_w[(h*32+o)*128+j] + en2_b[h*32+o] )
// atomically accumulated into agg[dst[e]*32+o]
__global__ void __launch_bounds__(256)
k_edge_msg(const float* __restrict__ e_feat,
           const int* __restrict__ src, const int* __restrict__ dst,
           const float* __restrict__ en1_w, const float* __restrict__ en1_b,
           const float* __restrict__ en2_w, const float* __restrict__ en2_b,
           const float* __restrict__ cur, float* __restrict__ agg, int E) {
    __shared__ float r_s[ET][EDGE_H + 4];     // stride 132 keeps float4 alignment
    __shared__ float wT_s[EDGE_H][HH + 1];    // W2h transposed: [j][o]
    __shared__ float x_s[ET][HH + 1];
    __shared__ float b2_s[HH * HH];
    int t = threadIdx.x;
    int e0 = blockIdx.x * ET;

    for (int i = t; i < HH * HH; i += 256) b2_s[i] = en2_b[i];

    // gather x = cur[src[e]]
    for (int i = t; i < ET * HH; i += 256) {
        int el = i >> 5, h = i & 31;
        int e = e0 + el;
        x_s[el][h] = (e < E) ? cur[(size_t)src[e] * HH + h] : 0.f;
    }

    // compute r = relu(e_feat @ en1_w^T + en1_b); 4 threads per edge, 32 j's each
    {
        int el = t >> 2;
        int j0 = (t & 3) * 32;
        int e = e0 + el;
        float ef[EDGE_IN];
        #pragma unroll
        for (int k = 0; k < EDGE_IN; ++k)
            ef[k] = (e < E) ? e_feat[(size_t)e * EDGE_IN + k] : 0.f;
        for (int jj = 0; jj < 32; ++jj) {
            int j = j0 + jj;
            float acc = en1_b[j];
            #pragma unroll
            for (int k = 0; k < EDGE_IN; ++k) acc += ef[k] * en1_w[j * EDGE_IN + k];
            r_s[el][j] = fmaxf(acc, 0.f);
        }
    }

    int o = t & 31, eg = t >> 5;  // thread owns output col o for 8 edges eg*8..eg*8+7
    float acc[8];
    #pragma unroll
    for (int k = 0; k < 8; ++k) acc[k] = 0.f;

    for (int h = 0; h < HH; ++h) {
        __syncthreads();  // also covers the r/x staging before first iteration
        // stage W2h transposed: wT_s[j][o'] = en2_w[(h*32+o')*128 + j]; coalesced global read
        #pragma unroll
        for (int i = 0; i < 16; ++i) {
            int idx = t + i * 256;
            int op = idx >> 7, j = idx & 127;
            wT_s[j][op] = en2_w[(size_t)(h * HH + op) * EDGE_H + j];
        }
        __syncthreads();
        float S[8];
        #pragma unroll
        for (int k = 0; k < 8; ++k) S[k] = 0.f;
        for (int j = 0; j < EDGE_H; j += 4) {
            float w0 = wT_s[j][o], w1 = wT_s[j + 1][o], w2 = wT_s[j + 2][o], w3 = wT_s[j + 3][o];
            #pragma unroll
            for (int k = 0; k < 8; ++k) {
                const float4 r4 = *(const float4*)&r_s[eg * 8 + k][j];  // broadcast across lanes
                S[k] += r4.x * w0 + r4.y * w1 + r4.z * w2 + r4.w * w3;
            }
        }
        float bb = b2_s[h * HH + o];
        #pragma unroll
        for (int k = 0; k < 8; ++k)
            acc[k] += x_s[eg * 8 + k][h] * (S[k] + bb);
    }
    #pragma unroll
    for (int k = 0; k < 8; ++k) {
        int e = e0 + eg * 8 + k;
        if (e < E) atomicAdd(&agg[(size_t)dst[e] * HH + o], acc[k]);
    }
}

// ---------------- node update: conv/residual/lin1/relu ----------------
__global__ void k_node_update(const float* __restrict__ agg, const float* __restrict__ cur,
                              const float* __restrict__ h0, const float* __restrict__ conv_bias,
                              const float* __restrict__ lin1_w, const float* __restrict__ lin1_b,
                              float* __restrict__ nxt, int n) {
    __shared__ float t_s[8][HH + 1];
    __shared__ float w_s[HH][HH + 1];
    int t = threadIdx.x;
    for (int i = t; i < HH * HH; i += 256) w_s[i >> 5][i & 31] = lin1_w[i];
    int nl = t >> 5, h = t & 31;
    int nn = blockIdx.x * 8 + nl;
    float tv = 0.f;
    if (nn < n) {
        size_t idx = (size_t)nn * HH + h;
        float conv = agg[idx] + cur[idx] + conv_bias[h];
        tv = 0.5f * conv + 0.5f * h0[idx];
    }
    t_s[nl][h] = tv;
    __syncthreads();
    if (nn < n) {
        const float BETA = 1.0f / 3.0f;
        float d = lin1_b[h];
        #pragma unroll
        for (int k = 0; k < HH; ++k) d += t_s[nl][k] * w_s[h][k];
        float v = BETA * d + (1.0f - BETA) * tv;
        nxt[(size_t)nn * HH + h] = fmaxf(v, 0.f);
    }
}

// ---------------- BN batch statistics: per-column sum and sumsq ----------------
__global__ void k_bn_stats(const float* __restrict__ out, float* __restrict__ stats, int n) {
    int t = threadIdx.x;
    int h = t & 31, rg = t >> 5;
    float s = 0.f, s2 = 0.f;
    for (int nn = blockIdx.x * 8 + rg; nn < n; nn += gridDim.x * 8) {
        float v = out[(size_t)nn * HH + h];
        s += v;
        s2 += v * v;
    }
    __shared__ float sh[256], sh2[256];
    sh[t] = s; sh2[t] = s2;
    __syncthreads();
    if (rg == 0) {
        #pragma unroll
        for (int g = 1; g < 8; ++g) { s += sh[g * 32 + h]; s2 += sh2[g * 32 + h]; }
        atomicAdd(&stats[h], s);
        atomicAdd(&stats[32 + h], s2);
    }
}

// ---------------- BN apply + y_sigmoid head; also stores y_bn for edge head ----------------
__global__ void k_node_out(const float* __restrict__ out, const float* __restrict__ stats,
                           const float* __restrict__ gamma, const float* __restrict__ beta,
                           const float* __restrict__ ylin_w, const float* __restrict__ ylin_b,
                           float* __restrict__ y_bn, float* __restrict__ y_sig, int n) {
    int nn = blockIdx.x * blockDim.x + threadIdx.x;
    if (nn >= n) return;
    float inv_n = 1.f / (float)n;
    float yb[HH];
    #pragma unroll
    for (int h = 0; h < HH; ++h) {
        float mu = stats[h] * inv_n;
        float var = stats[32 + h] * inv_n - mu * mu;
        float v = out[(size_t)nn * HH + h];
        yb[h] = (v - mu) * rsqrtf(var + 1e-5f) * gamma[h] + beta[h];
    }
    #pragma unroll
    for (int h = 0; h < HH; ++h) y_bn[(size_t)nn * HH + h] = yb[h];
    #pragma unroll
    for (int c = 0; c < 3; ++c) {
        float d = ylin_b[c];
        #pragma unroll
        for (int h = 0; h < HH; ++h) d += yb[h] * ylin_w[c * HH + h];
        y_sig[(size_t)nn * 3 + c] = 1.f / (1.f + expf(-d));
    }
}

// ---------------- edge-hop head ----------------
__global__ void k_edge_hop(const float* __restrict__ y_bn, const int* __restrict__ sl,
                           const int* __restrict__ dl, const float* __restrict__ w,
                           const float* __restrict__ b, float* __restrict__ outp, int e2) {
    int e = blockIdx.x * blockDim.x + threadIdx.x;
    if (e >= e2) return;
    const float4* a = (const float4*)(y_bn + (size_t)sl[e] * HH);
    const float4* c = (const float4*)(y_bn + (size_t)dl[e] * HH);
    float d = b[0];
    #pragma unroll
    for (int q = 0; q < 8; ++q) {
        float4 av = a[q], cv = c[q];
        float4 wv = ((const float4*)w)[q];
        d += av.x * cv.x * wv.x + av.y * cv.y * wv.y + av.z * cv.z * wv.z + av.w * cv.w * wv.w;
    }
    outp[e] = 1.f / (1.f + expf(-d));
}

extern "C" void kernel_launch(void* const* d_in, const int* in_sizes, int n_in,
                              void* d_out, int out_size, void* d_ws, size_t ws_size,
                              hipStream_t stream) {
    const float* n_feat   = (const float*)d_in[0];
    const float* e_feat   = (const float*)d_in[1];
    const int*   src      = (const int*)d_in[2];
    const int*   dst      = (const int*)d_in[3];
    const int*   src_list = (const int*)d_in[4];
    const int*   dst_list = (const int*)d_in[5];
    const float* lin0_w   = (const float*)d_in[6];
    const float* lin0_b   = (const float*)d_in[7];
    const float* en1_w    = (const float*)d_in[8];
    const float* en1_b    = (const float*)d_in[9];
    const float* en2_w    = (const float*)d_in[10];
    const float* en2_b    = (const float*)d_in[11];
    const float* conv_bias= (const float*)d_in[12];
    const float* lin1_w   = (const float*)d_in[13];
    const float* lin1_b   = (const float*)d_in[14];
    const float* bn_gamma = (const float*)d_in[15];
    const float* bn_beta  = (const float*)d_in[16];
    const float* ylin_w   = (const float*)d_in[17];
    const float* ylin_b   = (const float*)d_in[18];
    const float* ylin2_w  = (const float*)d_in[19];
    const float* ylin2_b  = (const float*)d_in[20];

    int n  = in_sizes[0] / NODE_IN;
    int E  = in_sizes[1] / EDGE_IN;
    int e2 = in_sizes[4];

    float* ws    = (float*)d_ws;
    size_t nh    = (size_t)n * HH;
    float* out_a = ws;
    float* out_b = out_a + nh;
    float* h0    = out_b + nh;
    float* agg   = h0 + nh;
    float* y_bn  = agg + nh;
    float* stats = y_bn + nh;   // 64 floats

    k_lin0<<<(n + 7) / 8, 256, 0, stream>>>(n_feat, lin0_w, lin0_b, out_a, h0, n);

    const float* cur = out_a;
    float* nxt = out_b;
    for (int s = 0; s < 3; ++s) {
        hipMemsetAsync(agg, 0, nh * sizeof(float), stream);
        k_edge_msg<<<(E + ET - 1) / ET, 256, 0, stream>>>(
            e_feat, src, dst, en1_w, en1_b, en2_w, en2_b, cur, agg, E);
        k_node_update<<<(n + 7) / 8, 256, 0, stream>>>(
            agg, cur, h0, conv_bias, lin1_w, lin1_b, nxt, n);
        float* t = (float*)cur; cur = nxt; nxt = t;
    }

    hipMemsetAsync(stats, 0, 64 * sizeof(float), stream);
    k_bn_stats<<<256, 256, 0, stream>>>(cur, stats, n);

    float* y_sig = (float*)d_out;
    float* e_out = y_sig + (size_t)n * 3;
    k_node_out<<<(n + 255) / 256, 256, 0, stream>>>(
        cur, stats, bn_gamma, bn_beta, ylin_w, ylin_b, y_bn, y_sig, n);
    k_edge_hop<<<(e2 + 255) / 256, 256, 0, stream>>>(
        y_bn, src_list, dst_list, ylin2_w, ylin2_b, e_out, e2);
}

// Round 2
// 360.364 us; speedup vs baseline: 7.3042x; 7.3042x over previous
//
#include <hip/hip_runtime.h>
#include <hip/hip_bf16.h>
#include <math.h>

#define HH 32
#define NODE_IN 64
#define EDGE_IN 16
#define EDGE_H 128
#define M_TILE 64   // edges per block in MFMA edge kernel

typedef __attribute__((ext_vector_type(8))) short bf16x8;
typedef __attribute__((ext_vector_type(4))) float f32x4;

__device__ inline unsigned short f2bf(float f) {
    union { float f; unsigned int u; } v; v.f = f;
    unsigned int r = v.u + 0x7fff + ((v.u >> 16) & 1);   // RNE (inputs never NaN)
    return (unsigned short)(r >> 16);
}

// ---------------- prep: W2 f32 -> bf16 (layout [n][j], same as en2_w) ----------------
__global__ void k_prep_w2(const float* __restrict__ en2_w, unsigned short* __restrict__ W2b) {
    int i = blockIdx.x * 256 + threadIdx.x;
    W2b[i] = f2bf(en2_w[i]);
}

// ---------------- prep: R = relu(e_feat @ en1_w^T + en1_b) -> bf16 [E_pad][128] ----------------
__global__ void k_prep_r(const float* __restrict__ e_feat, const float* __restrict__ en1_w,
                         const float* __restrict__ en1_b, unsigned short* __restrict__ Rb, int E) {
    __shared__ float w1_s[EDGE_H][EDGE_IN];
    __shared__ float b1_s[EDGE_H];
    int t = threadIdx.x;
    for (int i = t; i < EDGE_H * EDGE_IN; i += 256) w1_s[i >> 4][i & 15] = en1_w[i];
    for (int i = t; i < EDGE_H; i += 256) b1_s[i] = en1_b[i];
    __syncthreads();
    int e = blockIdx.x * 32 + (t >> 3);
    int j0 = (t & 7) * 16;
    unsigned short rr[16];
    if (e < E) {
        float ef[EDGE_IN];
        #pragma unroll
        for (int q = 0; q < 4; ++q) {
            float4 v = ((const float4*)(e_feat + (size_t)e * EDGE_IN))[q];
            ef[q * 4 + 0] = v.x; ef[q * 4 + 1] = v.y; ef[q * 4 + 2] = v.z; ef[q * 4 + 3] = v.w;
        }
        #pragma unroll
        for (int jj = 0; jj < 16; ++jj) {
            int j = j0 + jj;
            float acc = b1_s[j];
            #pragma unroll
            for (int k = 0; k < EDGE_IN; ++k) acc += ef[k] * w1_s[j][k];
            rr[jj] = f2bf(fmaxf(acc, 0.f));
        }
    } else {
        #pragma unroll
        for (int jj = 0; jj < 16; ++jj) rr[jj] = 0;   // zero-pad: avoids NaN garbage in MFMA
    }
    uint4* dst = (uint4*)(Rb + (size_t)e * EDGE_H + j0);
    dst[0] = *(const uint4*)&rr[0];
    dst[1] = *(const uint4*)&rr[8];
}

// ---------------- lin0: out = relu(n_feat @ lin0_w^T + b), h0 = out ----------------
__global__ void k_lin0(const float* __restrict__ nf, const float* __restrict__ w,
                       const float* __restrict__ b, float* __restrict__ out,
                       float* __restrict__ h0, int n) {
    __shared__ float nf_s[8][NODE_IN];
    __shared__ float w_s[HH][NODE_IN + 1];
    int t = threadIdx.x;
    for (int i = t; i < HH * NODE_IN; i += 256) w_s[i / NODE_IN][i % NODE_IN] = w[i];
    int n0 = blockIdx.x * 8;
    for (int i = t; i < 8 * NODE_IN; i += 256) {
        int nl = i / NODE_IN, k = i % NODE_IN;
        int nn = n0 + nl;
        nf_s[nl][k] = (nn < n) ? nf[(size_t)nn * NODE_IN + k] : 0.f;
    }
    __syncthreads();
    int nl = t >> 5, h = t & 31;
    int nn = n0 + nl;
    if (nn < n) {
        float acc = b[h];
        #pragma unroll
        for (int k = 0; k < NODE_IN; ++k) acc += nf_s[nl][k] * w_s[h][k];
        acc = fmaxf(acc, 0.f);
        out[(size_t)nn * HH + h] = acc;
        h0[(size_t)nn * HH + h] = acc;
    }
}

// ---------------- MFMA edge kernel ----------------
// C[e, h*32+o] = sum_j R[e,j] * W2[h*32+o, j]   (MFMA, bf16, f32 accum)
// msg[e,o] = sum_h x[e,h] * (C[e,h*32+o] + b2[h*32+o]); atomic-scatter to agg[dst[e]]
__global__ void __launch_bounds__(256, 2)
k_edge_mfma(const unsigned short* __restrict__ Rb, const unsigned short* __restrict__ W2b,
            const float* __restrict__ b2, const float* __restrict__ cur,
            const int* __restrict__ src, const int* __restrict__ dst,
            float* __restrict__ agg, int E) {
    __shared__ float x_t[HH][68];            // x transposed [h][e], stride 68 (16B-aligned rows)
    __shared__ float b2_s[HH * HH];
    __shared__ float msg_s[4][M_TILE * 33];  // per-wave partials, stride 33 rows
    int t = threadIdx.x;
    int wave = t >> 6, l = t & 63;
    int e0 = blockIdx.x * M_TILE;

    for (int i = t; i < HH * HH; i += 256) b2_s[i] = b2[i];

    // gather x[e][:] = cur[src[e]][:], store transposed
    for (int i = t; i < M_TILE * 8; i += 256) {
        int el = i >> 3, c = i & 7;
        int e = e0 + el;
        float4 v = make_float4(0.f, 0.f, 0.f, 0.f);
        if (e < E) v = ((const float4*)(cur + (size_t)src[e] * HH))[c];
        x_t[c * 4 + 0][el] = v.x; x_t[c * 4 + 1][el] = v.y;
        x_t[c * 4 + 2][el] = v.z; x_t[c * 4 + 3][el] = v.w;
    }
    __syncthreads();

    int lo = l & 15, lq = l >> 4;

    // A fragments: R rows e0..e0+63, kept in registers across all h
    bf16x8 afrag[4][4];
    #pragma unroll
    for (int m = 0; m < 4; ++m)
        #pragma unroll
        for (int ks = 0; ks < 4; ++ks) {
            size_t row = (size_t)(e0 + m * 16 + lo);
            afrag[m][ks] = *(const bf16x8*)(Rb + row * EDGE_H + ks * 32 + lq * 8);
        }

    float msg_acc[4][2][4];
    #pragma unroll
    for (int m = 0; m < 4; ++m)
        #pragma unroll
        for (int nn = 0; nn < 2; ++nn)
            #pragma unroll
            for (int r = 0; r < 4; ++r) msg_acc[m][nn][r] = 0.f;

    for (int h8 = 0; h8 < 8; ++h8) {
        int h = wave * 8 + h8;
        // B fragments straight from global (L2-resident, 256 KB total)
        bf16x8 bfrag[2][4];
        #pragma unroll
        for (int nn = 0; nn < 2; ++nn)
            #pragma unroll
            for (int ks = 0; ks < 4; ++ks) {
                size_t col = (size_t)(h * HH + nn * 16 + lo);
                bfrag[nn][ks] = *(const bf16x8*)(W2b + col * EDGE_H + ks * 32 + lq * 8);
            }
        f32x4 acc[4][2];
        #pragma unroll
        for (int m = 0; m < 4; ++m)
            #pragma unroll
            for (int nn = 0; nn < 2; ++nn) acc[m][nn] = (f32x4){0.f, 0.f, 0.f, 0.f};
        #pragma unroll
        for (int ks = 0; ks < 4; ++ks)
            #pragma unroll
            for (int m = 0; m < 4; ++m)
                #pragma unroll
                for (int nn = 0; nn < 2; ++nn)
                    acc[m][nn] = __builtin_amdgcn_mfma_f32_16x16x32_bf16(
                        afrag[m][ks], bfrag[nn][ks], acc[m][nn], 0, 0, 0);
        // epilogue: msg += x[e,h] * (C + b2)
        #pragma unroll
        for (int m = 0; m < 4; ++m) {
            const float4 xv = *(const float4*)&x_t[h][m * 16 + lq * 4];
            #pragma unroll
            for (int nn = 0; nn < 2; ++nn) {
                float bb = b2_s[h * HH + nn * 16 + lo];
                msg_acc[m][nn][0] += xv.x * (acc[m][nn][0] + bb);
                msg_acc[m][nn][1] += xv.y * (acc[m][nn][1] + bb);
                msg_acc[m][nn][2] += xv.z * (acc[m][nn][2] + bb);
                msg_acc[m][nn][3] += xv.w * (acc[m][nn][3] + bb);
            }
        }
    }

    // write per-wave partials (stride 33 -> conflict-free across lq)
    #pragma unroll
    for (int m = 0; m < 4; ++m)
        #pragma unroll
        for (int nn = 0; nn < 2; ++nn)
            #pragma unroll
            for (int r = 0; r < 4; ++r) {
                int row = m * 16 + lq * 4 + r, col = nn * 16 + lo;
                msg_s[wave][row * 33 + col] = msg_acc[m][nn][r];
            }
    __syncthreads();

    // reduce across 4 waves + scatter
    for (int i = t; i < M_TILE * HH; i += 256) {
        int row = i >> 5, col = i & 31;
        float s = msg_s[0][row * 33 + col] + msg_s[1][row * 33 + col]
                + msg_s[2][row * 33 + col] + msg_s[3][row * 33 + col];
        int e = e0 + row;
        if (e < E) atomicAdd(&agg[(size_t)dst[e] * HH + col], s);
    }
}

// ---------------- node update: conv/residual/lin1/relu ----------------
__global__ void k_node_update(const float* __restrict__ agg, const float* __restrict__ cur,
                              const float* __restrict__ h0, const float* __restrict__ conv_bias,
                              const float* __restrict__ lin1_w, const float* __restrict__ lin1_b,
                              float* __restrict__ nxt, int n) {
    __shared__ float t_s[8][HH + 1];
    __shared__ float w_s[HH][HH + 1];
    int t = threadIdx.x;
    for (int i = t; i < HH * HH; i += 256) w_s[i >> 5][i & 31] = lin1_w[i];
    int nl = t >> 5, h = t & 31;
    int nn = blockIdx.x * 8 + nl;
    float tv = 0.f;
    if (nn < n) {
        size_t idx = (size_t)nn * HH + h;
        float conv = agg[idx] + cur[idx] + conv_bias[h];
        tv = 0.5f * conv + 0.5f * h0[idx];
    }
    t_s[nl][h] = tv;
    __syncthreads();
    if (nn < n) {
        const float BETA = 1.0f / 3.0f;
        float d = lin1_b[h];
        #pragma unroll
        for (int k = 0; k < HH; ++k) d += t_s[nl][k] * w_s[h][k];
        float v = BETA * d + (1.0f - BETA) * tv;
        nxt[(size_t)nn * HH + h] = fmaxf(v, 0.f);
    }
}

// ---------------- BN batch statistics ----------------
__global__ void k_bn_stats(const float* __restrict__ out, float* __restrict__ stats, int n) {
    int t = threadIdx.x;
    int h = t & 31, rg = t >> 5;
    float s = 0.f, s2 = 0.f;
    for (int nn = blockIdx.x * 8 + rg; nn < n; nn += gridDim.x * 8) {
        float v = out[(size_t)nn * HH + h];
        s += v; s2 += v * v;
    }
    __shared__ float sh[256], sh2[256];
    sh[t] = s; sh2[t] = s2;
    __syncthreads();
    if (rg == 0) {
        #pragma unroll
        for (int g = 1; g < 8; ++g) { s += sh[g * 32 + h]; s2 += sh2[g * 32 + h]; }
        atomicAdd(&stats[h], s);
        atomicAdd(&stats[32 + h], s2);
    }
}

// ---------------- BN apply + y_sigmoid head ----------------
__global__ void k_node_out(const float* __restrict__ out, const float* __restrict__ stats,
                           const float* __restrict__ gamma, const float* __restrict__ beta,
                           const float* __restrict__ ylin_w, const float* __restrict__ ylin_b,
                           float* __restrict__ y_bn, float* __restrict__ y_sig, int n) {
    int nn = blockIdx.x * blockDim.x + threadIdx.x;
    if (nn >= n) return;
    float inv_n = 1.f / (float)n;
    float yb[HH];
    #pragma unroll
    for (int h = 0; h < HH; ++h) {
        float mu = stats[h] * inv_n;
        float var = stats[32 + h] * inv_n - mu * mu;
        float v = out[(size_t)nn * HH + h];
        yb[h] = (v - mu) * rsqrtf(var + 1e-5f) * gamma[h] + beta[h];
    }
    #pragma unroll
    for (int h = 0; h < HH; ++h) y_bn[(size_t)nn * HH + h] = yb[h];
    #pragma unroll
    for (int c = 0; c < 3; ++c) {
        float d = ylin_b[c];
        #pragma unroll
        for (int h = 0; h < HH; ++h) d += yb[h] * ylin_w[c * HH + h];
        y_sig[(size_t)nn * 3 + c] = 1.f / (1.f + expf(-d));
    }
}

// ---------------- edge-hop head ----------------
__global__ void k_edge_hop(const float* __restrict__ y_bn, const int* __restrict__ sl,
                           const int* __restrict__ dl, const float* __restrict__ w,
                           const float* __restrict__ b, float* __restrict__ outp, int e2) {
    int e = blockIdx.x * blockDim.x + threadIdx.x;
    if (e >= e2) return;
    const float4* a = (const float4*)(y_bn + (size_t)sl[e] * HH);
    const float4* c = (const float4*)(y_bn + (size_t)dl[e] * HH);
    float d = b[0];
    #pragma unroll
    for (int q = 0; q < 8; ++q) {
        float4 av = a[q], cv = c[q];
        float4 wv = ((const float4*)w)[q];
        d += av.x * cv.x * wv.x + av.y * cv.y * wv.y + av.z * cv.z * wv.z + av.w * cv.w * wv.w;
    }
    outp[e] = 1.f / (1.f + expf(-d));
}

extern "C" void kernel_launch(void* const* d_in, const int* in_sizes, int n_in,
                              void* d_out, int out_size, void* d_ws, size_t ws_size,
                              hipStream_t stream) {
    const float* n_feat   = (const float*)d_in[0];
    const float* e_feat   = (const float*)d_in[1];
    const int*   src      = (const int*)d_in[2];
    const int*   dst      = (const int*)d_in[3];
    const int*   src_list = (const int*)d_in[4];
    const int*   dst_list = (const int*)d_in[5];
    const float* lin0_w   = (const float*)d_in[6];
    const float* lin0_b   = (const float*)d_in[7];
    const float* en1_w    = (const float*)d_in[8];
    const float* en1_b    = (const float*)d_in[9];
    const float* en2_w    = (const float*)d_in[10];
    const float* en2_b    = (const float*)d_in[11];
    const float* conv_bias= (const float*)d_in[12];
    const float* lin1_w   = (const float*)d_in[13];
    const float* lin1_b   = (const float*)d_in[14];
    const float* bn_gamma = (const float*)d_in[15];
    const float* bn_beta  = (const float*)d_in[16];
    const float* ylin_w   = (const float*)d_in[17];
    const float* ylin_b   = (const float*)d_in[18];
    const float* ylin2_w  = (const float*)d_in[19];
    const float* ylin2_b  = (const float*)d_in[20];

    int n  = in_sizes[0] / NODE_IN;
    int E  = in_sizes[1] / EDGE_IN;
    int e2 = in_sizes[4];
    int E_pad = (E + M_TILE - 1) & ~(M_TILE - 1);

    float* ws    = (float*)d_ws;
    size_t nh    = (size_t)n * HH;
    float* out_a = ws;
    float* out_b = out_a + nh;
    float* h0    = out_b + nh;
    float* agg   = h0 + nh;
    float* y_bn  = agg + nh;
    float* stats = y_bn + nh;                          // 64 floats
    unsigned short* W2b = (unsigned short*)(stats + 64);   // 1024*128 bf16
    unsigned short* Rb  = W2b + 1024 * EDGE_H;             // E_pad*128 bf16

    k_prep_w2<<<(1024 * EDGE_H) / 256, 256, 0, stream>>>(en2_w, W2b);
    k_prep_r<<<E_pad / 32, 256, 0, stream>>>(e_feat, en1_w, en1_b, Rb, E);
    k_lin0<<<(n + 7) / 8, 256, 0, stream>>>(n_feat, lin0_w, lin0_b, out_a, h0, n);

    const float* cur = out_a;
    float* nxt = out_b;
    for (int s = 0; s < 3; ++s) {
        hipMemsetAsync(agg, 0, nh * sizeof(float), stream);
        k_edge_mfma<<<E_pad / M_TILE, 256, 0, stream>>>(
            Rb, W2b, en2_b, cur, src, dst, agg, E);
        k_node_update<<<(n + 7) / 8, 256, 0, stream>>>(
            agg, cur, h0, conv_bias, lin1_w, lin1_b, nxt, n);
        float* t = (float*)cur; cur = nxt; nxt = t;
    }

    hipMemsetAsync(stats, 0, 64 * sizeof(float), stream);
    k_bn_stats<<<256, 256, 0, stream>>>(cur, stats, n);

    float* y_sig = (float*)d_out;
    float* e_out = y_sig + (size_t)n * 3;
    k_node_out<<<(n + 255) / 256, 256, 0, stream>>>(
        cur, stats, bn_gamma, bn_beta, ylin_w, ylin_b, y_bn, y_sig, n);
    k_edge_hop<<<(e2 + 255) / 256, 256, 0, stream>>>(
        y_bn, src_list, dst_list, ylin2_w, ylin2_b, e_out, e2);
}